// Round 2
// baseline (3614.304 us; speedup 1.0000x reference)
//
#include <hip/hip_runtime.h>

typedef __attribute__((ext_vector_type(8))) short short8;
typedef __attribute__((ext_vector_type(4))) float f32x4;

#define MFMA16 __builtin_amdgcn_mfma_f32_16x16x32_bf16

__device__ __forceinline__ unsigned short f2bf(float f){
  union { float f; unsigned int u; } v; v.f = f;
  unsigned int u = v.u + 0x7fffu + ((v.u >> 16) & 1u);  // RNE
  return (unsigned short)(u >> 16);
}
__device__ __forceinline__ float lo2f(unsigned int u){ union { unsigned int u; float f; } v; v.u = u << 16; return v.f; }
__device__ __forceinline__ float hi2f(unsigned int u){ union { unsigned int u; float f; } v; v.u = u & 0xffff0000u; return v.f; }

// ---------------- ws layout ----------------
// WT: all weights transposed to [N][K] bf16 (contiguous K per output col)
constexpr size_t WQKV_HSTR = 768*256;                       // per-head [768][256]
constexpr size_t W1T_OFF   = 8*WQKV_HSTR;                   // 8 x [256][512]
constexpr size_t W1T_HSTR  = 512*256;
constexpr size_t W2T_OFF   = W1T_OFF + 8*W1T_HSTR;          // 8 x [256][256]
constexpr size_t W2T_HSTR  = 256*256;
constexpr size_t OQKV_OFF  = W2T_OFF + 8*W2T_HSTR;          // [768][2048]
constexpr size_t OW1_OFF   = OQKV_OFF + (size_t)768*2048;   // [256][2304]
constexpr size_t OW2_OFF   = OW1_OFF + (size_t)256*2304;    // [256][256]
constexpr size_t WT_ELEMS  = OW2_OFF + (size_t)256*256;     // 5,373,952 elems (~10.25 MB)
constexpr size_t XP_OFFB   = (WT_ELEMS*2 + 255) & ~(size_t)255;      // bytes
constexpr size_t XP_BYTES  = (size_t)131072*256*2;                   // 64 MB
constexpr size_t FEATS_OFFB = XP_OFFB + XP_BYTES;           // chunked feats ring starts here

constexpr int LDX  = 264;   // xp tile stride (pad: 528B -> bank step 4)
constexpr int LDQ  = 776;   // qkv tile stride (1552B -> bank step 4)
constexpr int LDS2 = 72;    // k-chunk staging stride (144B -> bank step 4)

// ---------------- prep: transpose weights to bf16 [N][K] ----------------
__global__ void k_transpose(const float* __restrict__ src, unsigned short* __restrict__ dst,
                            int K, int N, long long srcStride, long long dstStride){
  const int i = blockIdx.x*256 + threadIdx.x;   // index into dst [N][K]
  const int b = blockIdx.y;
  const int n = i / K, k = i - n*K;
  dst[(size_t)b*dstStride + i] = f2bf(src[(size_t)b*srcStride + (size_t)k*N + n]);
}

// ---------------- xp = bf16(x + pos) ----------------
__global__ void k_xp(const float* __restrict__ x, const float* __restrict__ pos,
                     unsigned short* __restrict__ xp){
  const size_t i = ((size_t)blockIdx.x*256 + threadIdx.x) * 8;
  const int colb = (int)(i & 255);
  const int t = (int)((i >> 8) & 7);
  float4 a0 = *(const float4*)(x + i);
  float4 a1 = *(const float4*)(x + i + 4);
  float4 p0 = *(const float4*)(pos + t*256 + colb);
  float4 p1 = *(const float4*)(pos + t*256 + colb + 4);
  short8 o;
  o[0]=(short)f2bf(a0.x+p0.x); o[1]=(short)f2bf(a0.y+p0.y);
  o[2]=(short)f2bf(a0.z+p0.z); o[3]=(short)f2bf(a0.w+p0.w);
  o[4]=(short)f2bf(a1.x+p1.x); o[5]=(short)f2bf(a1.y+p1.y);
  o[6]=(short)f2bf(a1.z+p1.z); o[7]=(short)f2bf(a1.w+p1.w);
  *(short8*)(xp + i) = o;
}

// ---------------- per-head fused kernel ----------------
// grid (R/64, 8 heads), 512 threads = 8 waves. Tile = 64 rows = 8 batch groups.
// xp/feats pointers are pre-offset to the chunk base by the launcher.
__global__ __launch_bounds__(512, 2) void k_head(
    const unsigned short* __restrict__ xp,
    const unsigned short* __restrict__ WT,
    const float* __restrict__ hb1, const float* __restrict__ hb2,
    unsigned short* __restrict__ feats)
{
  __shared__ __align__(16) unsigned short xs[64*LDX];
  __shared__ __align__(16) unsigned short qs[64*LDQ];   // Q|K|V cols 0/256/512; later attn_out|h1
  __shared__ float aw[8][64];

  const int h    = blockIdx.y;
  const int r0   = blockIdx.x << 6;
  const int tid  = threadIdx.x;
  const int wave = tid >> 6;
  const int lane = tid & 63;
  const int l16  = lane & 15;
  const int lq   = lane >> 4;

  // load xp tile (64 x 256)
  {
    const int row = tid >> 3, c0 = (tid & 7) << 5;
    const short8* s = (const short8*)(xp + (size_t)(r0 + row)*256 + c0);
    short8* d = (short8*)(xs + row*LDX + c0);
    #pragma unroll
    for (int j = 0; j < 4; j++) d[j] = s[j];
  }
  __syncthreads();

  // QKV: [64,256] @ [256,768]; wave owns 96 cols
  {
    const unsigned short* W = WT + (size_t)h * WQKV_HSTR;
    f32x4 acc[4][6];
    #pragma unroll
    for (int m = 0; m < 4; m++)
      #pragma unroll
      for (int n = 0; n < 6; n++) acc[m][n] = (f32x4){0.f,0.f,0.f,0.f};
    #pragma unroll
    for (int kk = 0; kk < 8; kk++){
      const int ko = (kk << 5) + (lq << 3);
      short8 a[4];
      #pragma unroll
      for (int m = 0; m < 4; m++)
        a[m] = *(const short8*)(xs + (m*16 + l16)*LDX + ko);
      #pragma unroll
      for (int n = 0; n < 6; n++){
        const int col = wave*96 + n*16 + l16;
        short8 b = *(const short8*)(W + (size_t)col*256 + ko);
        #pragma unroll
        for (int m = 0; m < 4; m++)
          acc[m][n] = MFMA16(a[m], b, acc[m][n], 0, 0, 0);
      }
    }
    #pragma unroll
    for (int n = 0; n < 6; n++){
      const int col = wave*96 + n*16 + l16;
      #pragma unroll
      for (int m = 0; m < 4; m++)
        #pragma unroll
        for (int r = 0; r < 4; r++)
          qs[(m*16 + lq*4 + r)*LDQ + col] = f2bf(acc[m][n][r]);
    }
  }
  __syncthreads();

  // attention scores + causal softmax; wave <-> batch group, lane = (t,s)
  {
    const int t = lane >> 3, s = lane & 7;
    const unsigned short* Qr = qs + (wave*8 + t)*LDQ;
    const unsigned short* Kr = qs + (wave*8 + s)*LDQ + 256;
    float e = 0.f;
    #pragma unroll
    for (int c = 0; c < 256; c += 8){
      union { short8 v; unsigned int u[4]; } qa, kb;
      qa.v = *(const short8*)(Qr + c);
      kb.v = *(const short8*)(Kr + c);
      #pragma unroll
      for (int j = 0; j < 4; j++){
        e = fmaf(lo2f(qa.u[j]), lo2f(kb.u[j]), e);
        e = fmaf(hi2f(qa.u[j]), hi2f(kb.u[j]), e);
      }
    }
    e *= 0.0625f;                    // 1/sqrt(256)
    if (s > t) e = -1e30f;           // causal
    float mx = fmaxf(e, __shfl_xor(e, 1));
    mx = fmaxf(mx, __shfl_xor(mx, 2));
    mx = fmaxf(mx, __shfl_xor(mx, 4));
    float p = (s <= t) ? __expf(e - mx) : 0.f;
    float sum = p;
    sum += __shfl_xor(sum, 1);
    sum += __shfl_xor(sum, 2);
    sum += __shfl_xor(sum, 4);
    aw[wave][lane] = p / sum;
  }
  __syncthreads();

  // attn @ V -> qs cols 0..255 (overwrites Q)
  {
    const int t = lane >> 3, c8 = lane & 7;
    float o[32];
    #pragma unroll
    for (int j = 0; j < 32; j++) o[j] = 0.f;
    #pragma unroll
    for (int s = 0; s < 8; s++){
      const float w = aw[wave][t*8 + s];
      const unsigned short* Vr = qs + (wave*8 + s)*LDQ + 512 + (c8 << 5);
      #pragma unroll
      for (int jj = 0; jj < 4; jj++){
        union { short8 v; unsigned int u[4]; } vv;
        vv.v = *(const short8*)(Vr + jj*8);
        #pragma unroll
        for (int q = 0; q < 4; q++){
          o[jj*8 + 2*q]     = fmaf(w, lo2f(vv.u[q]), o[jj*8 + 2*q]);
          o[jj*8 + 2*q + 1] = fmaf(w, hi2f(vv.u[q]), o[jj*8 + 2*q + 1]);
        }
      }
    }
    unsigned short* Or = qs + (wave*8 + t)*LDQ + (c8 << 5);
    #pragma unroll
    for (int j = 0; j < 32; j++) Or[j] = f2bf(o[j]);
  }
  __syncthreads();

  // FFN1: cat(attn_out, xp) [64,512] @ [512,256]; wave owns 32 cols
  {
    const unsigned short* W = WT + W1T_OFF + (size_t)h * W1T_HSTR;
    f32x4 acc[4][2];
    #pragma unroll
    for (int m = 0; m < 4; m++){ acc[m][0] = (f32x4){0.f,0.f,0.f,0.f}; acc[m][1] = (f32x4){0.f,0.f,0.f,0.f}; }
    #pragma unroll
    for (int kk = 0; kk < 16; kk++){
      const int ko = (kk << 5) + (lq << 3);
      short8 a[4];
      #pragma unroll
      for (int m = 0; m < 4; m++)
        a[m] = (kk < 8) ? *(const short8*)(qs + (m*16 + l16)*LDQ + ko)
                        : *(const short8*)(xs + (m*16 + l16)*LDX + (ko - 256));
      #pragma unroll
      for (int n = 0; n < 2; n++){
        const int col = (wave << 5) + (n << 4) + l16;
        short8 b = *(const short8*)(W + (size_t)col*512 + ko);
        #pragma unroll
        for (int m = 0; m < 4; m++)
          acc[m][n] = MFMA16(a[m], b, acc[m][n], 0, 0, 0);
      }
    }
    #pragma unroll
    for (int n = 0; n < 2; n++){
      const int col = (wave << 5) + (n << 4) + l16;
      const float bv = hb1[(h << 8) + col];
      #pragma unroll
      for (int m = 0; m < 4; m++)
        #pragma unroll
        for (int r = 0; r < 4; r++)
          qs[(m*16 + lq*4 + r)*LDQ + 256 + col] = f2bf(fmaxf(acc[m][n][r] + bv, 0.f));
    }
  }
  __syncthreads();

  // FFN2: h1 [64,256] @ [256,256] -> feats slice
  {
    const unsigned short* W = WT + W2T_OFF + (size_t)h * W2T_HSTR;
    f32x4 acc[4][2];
    #pragma unroll
    for (int m = 0; m < 4; m++){ acc[m][0] = (f32x4){0.f,0.f,0.f,0.f}; acc[m][1] = (f32x4){0.f,0.f,0.f,0.f}; }
    #pragma unroll
    for (int kk = 0; kk < 8; kk++){
      const int ko = (kk << 5) + (lq << 3);
      short8 a[4];
      #pragma unroll
      for (int m = 0; m < 4; m++)
        a[m] = *(const short8*)(qs + (m*16 + l16)*LDQ + 256 + ko);
      #pragma unroll
      for (int n = 0; n < 2; n++){
        const int col = (wave << 5) + (n << 4) + l16;
        short8 b = *(const short8*)(W + (size_t)col*256 + ko);
        #pragma unroll
        for (int m = 0; m < 4; m++)
          acc[m][n] = MFMA16(a[m], b, acc[m][n], 0, 0, 0);
      }
    }
    #pragma unroll
    for (int n = 0; n < 2; n++){
      const int col = (wave << 5) + (n << 4) + l16;
      const float bv = hb2[(h << 8) + col];
      #pragma unroll
      for (int m = 0; m < 4; m++)
        #pragma unroll
        for (int r = 0; r < 4; r++)
          feats[(size_t)(r0 + m*16 + lq*4 + r)*2048 + (h << 8) + col] = f2bf(acc[m][n][r] + bv);
    }
  }
}

// ---------------- output-layer fused kernel ----------------
// feats/out pointers are pre-offset to the chunk base by the launcher.
__global__ __launch_bounds__(512, 2) void k_out(
    const unsigned short* __restrict__ feats,
    const unsigned short* __restrict__ WT,
    const float* __restrict__ ob1, const float* __restrict__ ob2,
    float* __restrict__ out)
{
  __shared__ __align__(16) unsigned short as2[2][64*LDS2];
  __shared__ __align__(16) unsigned short qs[64*LDQ];
  __shared__ float aw[8][64];

  const int r0   = blockIdx.x << 6;
  const int tid  = threadIdx.x;
  const int wave = tid >> 6;
  const int lane = tid & 63;
  const int l16  = lane & 15;
  const int lq   = lane >> 4;
  const int srow = tid >> 3, sc0 = (tid & 7) << 3;

  // QKV2: [64,2048] @ [2048,768], feats streamed in 64-wide K chunks (dbuf, 1 barrier/iter)
  {
    const unsigned short* W = WT + OQKV_OFF;
    f32x4 acc[4][6];
    #pragma unroll
    for (int m = 0; m < 4; m++)
      #pragma unroll
      for (int n = 0; n < 6; n++) acc[m][n] = (f32x4){0.f,0.f,0.f,0.f};
    for (int ch = 0; ch < 32; ch++){
      *(short8*)(as2[ch & 1] + srow*LDS2 + sc0) =
          *(const short8*)(feats + (size_t)(r0 + srow)*2048 + (ch << 6) + sc0);
      __syncthreads();
      #pragma unroll
      for (int k2 = 0; k2 < 2; k2++){
        const int ko = (k2 << 5) + (lq << 3);
        short8 a[4];
        #pragma unroll
        for (int m = 0; m < 4; m++)
          a[m] = *(const short8*)(as2[ch & 1] + (m*16 + l16)*LDS2 + ko);
        #pragma unroll
        for (int n = 0; n < 6; n++){
          const int col = wave*96 + n*16 + l16;
          short8 b = *(const short8*)(W + (size_t)col*2048 + (ch << 6) + ko);
          #pragma unroll
          for (int m = 0; m < 4; m++)
            acc[m][n] = MFMA16(a[m], b, acc[m][n], 0, 0, 0);
        }
      }
    }
    #pragma unroll
    for (int n = 0; n < 6; n++){
      const int col = wave*96 + n*16 + l16;
      #pragma unroll
      for (int m = 0; m < 4; m++)
        #pragma unroll
        for (int r = 0; r < 4; r++)
          qs[(m*16 + lq*4 + r)*LDQ + col] = f2bf(acc[m][n][r]);
    }
  }
  __syncthreads();

  // attention (identical structure to k_head)
  {
    const int t = lane >> 3, s = lane & 7;
    const unsigned short* Qr = qs + (wave*8 + t)*LDQ;
    const unsigned short* Kr = qs + (wave*8 + s)*LDQ + 256;
    float e = 0.f;
    #pragma unroll
    for (int c = 0; c < 256; c += 8){
      union { short8 v; unsigned int u[4]; } qa, kb;
      qa.v = *(const short8*)(Qr + c);
      kb.v = *(const short8*)(Kr + c);
      #pragma unroll
      for (int j = 0; j < 4; j++){
        e = fmaf(lo2f(qa.u[j]), lo2f(kb.u[j]), e);
        e = fmaf(hi2f(qa.u[j]), hi2f(kb.u[j]), e);
      }
    }
    e *= 0.0625f;
    if (s > t) e = -1e30f;
    float mx = fmaxf(e, __shfl_xor(e, 1));
    mx = fmaxf(mx, __shfl_xor(mx, 2));
    mx = fmaxf(mx, __shfl_xor(mx, 4));
    float p = (s <= t) ? __expf(e - mx) : 0.f;
    float sum = p;
    sum += __shfl_xor(sum, 1);
    sum += __shfl_xor(sum, 2);
    sum += __shfl_xor(sum, 4);
    aw[wave][lane] = p / sum;
  }
  __syncthreads();
  {
    const int t = lane >> 3, c8 = lane & 7;
    float o[32];
    #pragma unroll
    for (int j = 0; j < 32; j++) o[j] = 0.f;
    #pragma unroll
    for (int s = 0; s < 8; s++){
      const float w = aw[wave][t*8 + s];
      const unsigned short* Vr = qs + (wave*8 + s)*LDQ + 512 + (c8 << 5);
      #pragma unroll
      for (int jj = 0; jj < 4; jj++){
        union { short8 v; unsigned int u[4]; } vv;
        vv.v = *(const short8*)(Vr + jj*8);
        #pragma unroll
        for (int q = 0; q < 4; q++){
          o[jj*8 + 2*q]     = fmaf(w, lo2f(vv.u[q]), o[jj*8 + 2*q]);
          o[jj*8 + 2*q + 1] = fmaf(w, hi2f(vv.u[q]), o[jj*8 + 2*q + 1]);
        }
      }
    }
    unsigned short* Or = qs + (wave*8 + t)*LDQ + (c8 << 5);
    #pragma unroll
    for (int j = 0; j < 32; j++) Or[j] = f2bf(o[j]);
  }
  __syncthreads();

  // FFN1: cat(attn2, feats) K=2304
  {
    const unsigned short* W = WT + OW1_OFF;
    f32x4 acc[4][2];
    #pragma unroll
    for (int m = 0; m < 4; m++){ acc[m][0] = (f32x4){0.f,0.f,0.f,0.f}; acc[m][1] = (f32x4){0.f,0.f,0.f,0.f}; }
    #pragma unroll
    for (int kk = 0; kk < 8; kk++){               // k<256: attn_out from LDS
      const int ko = (kk << 5) + (lq << 3);
      short8 a[4];
      #pragma unroll
      for (int m = 0; m < 4; m++)
        a[m] = *(const short8*)(qs + (m*16 + l16)*LDQ + ko);
      #pragma unroll
      for (int n = 0; n < 2; n++){
        const int col = (wave << 5) + (n << 4) + l16;
        short8 b = *(const short8*)(W + (size_t)col*2304 + ko);
        #pragma unroll
        for (int m = 0; m < 4; m++)
          acc[m][n] = MFMA16(a[m], b, acc[m][n], 0, 0, 0);
      }
    }
    for (int ch = 0; ch < 32; ch++){              // k>=256: feats streamed
      *(short8*)(as2[ch & 1] + srow*LDS2 + sc0) =
          *(const short8*)(feats + (size_t)(r0 + srow)*2048 + (ch << 6) + sc0);
      __syncthreads();
      #pragma unroll
      for (int k2 = 0; k2 < 2; k2++){
        const int ko = (k2 << 5) + (lq << 3);
        short8 a[4];
        #pragma unroll
        for (int m = 0; m < 4; m++)
          a[m] = *(const short8*)(as2[ch & 1] + (m*16 + l16)*LDS2 + ko);
        #pragma unroll
        for (int n = 0; n < 2; n++){
          const int col = (wave << 5) + (n << 4) + l16;
          short8 b = *(const short8*)(W + (size_t)col*2304 + 256 + (ch << 6) + ko);
          #pragma unroll
          for (int m = 0; m < 4; m++)
            acc[m][n] = MFMA16(a[m], b, acc[m][n], 0, 0, 0);
        }
      }
    }
    #pragma unroll
    for (int n = 0; n < 2; n++){
      const int col = (wave << 5) + (n << 4) + l16;
      const float bv = ob1[col];
      #pragma unroll
      for (int m = 0; m < 4; m++)
        #pragma unroll
        for (int r = 0; r < 4; r++)
          qs[(m*16 + lq*4 + r)*LDQ + 256 + col] = f2bf(fmaxf(acc[m][n][r] + bv, 0.f));
    }
  }
  __syncthreads();

  // FFN2 -> out (fp32)
  {
    const unsigned short* W = WT + OW2_OFF;
    f32x4 acc[4][2];
    #pragma unroll
    for (int m = 0; m < 4; m++){ acc[m][0] = (f32x4){0.f,0.f,0.f,0.f}; acc[m][1] = (f32x4){0.f,0.f,0.f,0.f}; }
    #pragma unroll
    for (int kk = 0; kk < 8; kk++){
      const int ko = (kk << 5) + (lq << 3);
      short8 a[4];
      #pragma unroll
      for (int m = 0; m < 4; m++)
        a[m] = *(const short8*)(qs + (m*16 + l16)*LDQ + 256 + ko);
      #pragma unroll
      for (int n = 0; n < 2; n++){
        const int col = (wave << 5) + (n << 4) + l16;
        short8 b = *(const short8*)(W + (size_t)col*256 + ko);
        #pragma unroll
        for (int m = 0; m < 4; m++)
          acc[m][n] = MFMA16(a[m], b, acc[m][n], 0, 0, 0);
      }
    }
    #pragma unroll
    for (int n = 0; n < 2; n++){
      const int col = (wave << 5) + (n << 4) + l16;
      const float bv = ob2[col];
      #pragma unroll
      for (int m = 0; m < 4; m++)
        #pragma unroll
        for (int r = 0; r < 4; r++)
          out[(size_t)(r0 + m*16 + lq*4 + r)*256 + col] = acc[m][n][r] + bv;
    }
  }
}

extern "C" void kernel_launch(void* const* d_in, const int* in_sizes, int n_in,
                              void* d_out, int out_size, void* d_ws, size_t ws_size,
                              hipStream_t stream) {
  (void)n_in; (void)out_size;
  const float* x    = (const float*)d_in[0];
  const float* pos  = (const float*)d_in[1];
  const float* hWq  = (const float*)d_in[2];
  const float* hWk  = (const float*)d_in[3];
  const float* hWv  = (const float*)d_in[4];
  const float* hW1  = (const float*)d_in[5];
  const float* hb1  = (const float*)d_in[6];
  const float* hW2  = (const float*)d_in[7];
  const float* hb2  = (const float*)d_in[8];
  const float* oWq  = (const float*)d_in[9];
  const float* oWk  = (const float*)d_in[10];
  const float* oWv  = (const float*)d_in[11];
  const float* oW1  = (const float*)d_in[12];
  const float* ob1  = (const float*)d_in[13];
  const float* oW2  = (const float*)d_in[14];
  const float* ob2  = (const float*)d_in[15];

  unsigned short* WT    = (unsigned short*)d_ws;
  unsigned short* xp    = (unsigned short*)((char*)d_ws + XP_OFFB);
  unsigned short* feats = (unsigned short*)((char*)d_ws + FEATS_OFFB);
  float* out = (float*)d_out;

  const long long BT = in_sizes[0] / 256;   // 131072

  // Chunk the feats intermediate to whatever fits in the remaining workspace.
  // Deterministic (depends only on ws_size) -> graph-capture safe.
  const size_t featsCapB = (ws_size > FEATS_OFFB) ? (ws_size - FEATS_OFFB) : 0;
  long long R = (long long)(featsCapB / (size_t)(2048*2));
  if (R > BT) R = BT;
  R &= ~63LL;
  if (R < 64) R = 64;   // last-ditch (should not happen)

  // weight transposes (bf16, [N][K])
  k_transpose<<<dim3(256,8),  256, 0, stream>>>(hWq, WT,                      256, 256, 65536, 196608);
  k_transpose<<<dim3(256,8),  256, 0, stream>>>(hWk, WT + 65536,              256, 256, 65536, 196608);
  k_transpose<<<dim3(256,8),  256, 0, stream>>>(hWv, WT + 131072,             256, 256, 65536, 196608);
  k_transpose<<<dim3(512,8),  256, 0, stream>>>(hW1, WT + W1T_OFF,            512, 256, 131072, 131072);
  k_transpose<<<dim3(256,8),  256, 0, stream>>>(hW2, WT + W2T_OFF,            256, 256, 65536, 65536);
  k_transpose<<<dim3(2048,1), 256, 0, stream>>>(oWq, WT + OQKV_OFF,           2048, 256, 0, 0);
  k_transpose<<<dim3(2048,1), 256, 0, stream>>>(oWk, WT + OQKV_OFF + 524288,  2048, 256, 0, 0);
  k_transpose<<<dim3(2048,1), 256, 0, stream>>>(oWv, WT + OQKV_OFF + 1048576, 2048, 256, 0, 0);
  k_transpose<<<dim3(2304,1), 256, 0, stream>>>(oW1, WT + OW1_OFF,            2304, 256, 0, 0);
  k_transpose<<<dim3(256,1),  256, 0, stream>>>(oW2, WT + OW2_OFF,            256, 256, 0, 0);

  k_xp<<<(int)(BT/8), 256, 0, stream>>>(x, pos, xp);

  for (long long base = 0; base < BT; base += R) {
    const long long Rc = (BT - base < R) ? (BT - base) : R;
    const int mt = (int)(Rc / 64);
    k_head<<<dim3(mt, 8), 512, 0, stream>>>(xp + base*256, WT, hb1, hb2, feats);
    k_out <<<dim3(mt),    512, 0, stream>>>(feats, WT, ob1, ob2, out + base*256);
  }
}